// Round 3
// baseline (793.448 us; speedup 1.0000x reference)
//
#include <hip/hip_runtime.h>

#define D 64
#define SLOPE 0.2f
#define BN_EPS 1e-5f

// bf16 pack/unpack (RNE)
static __device__ __forceinline__ unsigned pk_bf16(float fx, float fy) {
    unsigned bx = __float_as_uint(fx);
    unsigned by = __float_as_uint(fy);
    bx = (bx + 0x7fffu + ((bx >> 16) & 1u)) >> 16;
    by = (by + 0x7fffu + ((by >> 16) & 1u)) & 0xffff0000u;
    return bx | by;
}
static __device__ __forceinline__ float bf_lo(unsigned u) { return __uint_as_float(u << 16); }
static __device__ __forceinline__ float bf_hi(unsigned u) { return __uint_as_float(u & 0xffff0000u); }

// ---------------------------------------------------------------------------
// CSR build
__global__ void k_count(const int* __restrict__ dst, int* __restrict__ cnt, int E) {
    for (int e = blockIdx.x * blockDim.x + threadIdx.x; e < E; e += gridDim.x * blockDim.x)
        atomicAdd(&cnt[dst[e]], 1);
}

__global__ void k_dinv(const int* __restrict__ cnt, float* __restrict__ dinv, int N) {
    for (int i = blockIdx.x * blockDim.x + threadIdx.x; i < N; i += gridDim.x * blockDim.x)
        dinv[i] = rsqrtf((float)cnt[i] + 1.0f);
}

__global__ void k_scan1(const int* __restrict__ cnt, int* __restrict__ rp,
                        int* __restrict__ bsum, int N) {
    __shared__ int l[256];
    const int t = threadIdx.x;
    const int i = blockIdx.x * 256 + t;
    const int v = (i < N) ? cnt[i] : 0;
    l[t] = v;
    __syncthreads();
    for (int off = 1; off < 256; off <<= 1) {
        int x = l[t];
        if (t >= off) x += l[t - off];
        __syncthreads();
        l[t] = x;
        __syncthreads();
    }
    if (i < N) rp[i] = l[t] - v;
    if (t == 255) bsum[blockIdx.x] = l[255];
}

__global__ void k_scan2(int* __restrict__ bsum, int* __restrict__ rp, int B, int E, int N) {
    __shared__ int l[512];
    const int t = threadIdx.x;
    const int v = (t < B) ? bsum[t] : 0;
    l[t] = v;
    __syncthreads();
    for (int off = 1; off < 512; off <<= 1) {
        int x = l[t];
        if (t >= off) x += l[t - off];
        __syncthreads();
        l[t] = x;
        __syncthreads();
    }
    if (t < B) bsum[t] = l[t] - v;
    if (t == 0) rp[N] = E;
}

__global__ void k_scan3(int* __restrict__ rp, const int* __restrict__ bsum, int N) {
    const int i = blockIdx.x * blockDim.x + threadIdx.x;
    if (i < N) rp[i] += bsum[i >> 8];
}

__global__ void k_scatter(const int* __restrict__ src, const int* __restrict__ dst,
                          const int* __restrict__ rp, int* __restrict__ cur,
                          int* __restrict__ colbuf, int E) {
    for (int e = blockIdx.x * blockDim.x + threadIdx.x; e < E; e += gridDim.x * blockDim.x) {
        const int d = dst[e];
        const int pos = rp[d] + atomicAdd(&cur[d], 1);
        colbuf[pos] = src[e];
    }
}

// ---------------------------------------------------------------------------
// ybf[row] = pack_bf16( ((AFFINE? sc*x+sh : x) @ W) * dinv[row] )   [N x 32 uints]
template <bool AFFINE>
__global__ void k_gemm(const float* __restrict__ x, const float* __restrict__ W,
                       const float* __restrict__ ss, const float* __restrict__ dinv,
                       unsigned* __restrict__ ybf, int N) {
    __shared__ float Wl[D * D];
    for (int i = threadIdx.x; i < D * D; i += blockDim.x) Wl[i] = W[i];
    __syncthreads();

    const int lane = threadIdx.x & 63;
    const int wib  = threadIdx.x >> 6;
    float sc = 1.0f, sh = 0.0f;
    if (AFFINE) { sc = ss[lane]; sh = ss[64 + lane]; }

    for (int row = blockIdx.x * 4 + wib; row < N; row += gridDim.x * 4) {
        float xo = x[(size_t)row * D + lane];
        if (AFFINE) xo = fmaf(sc, xo, sh);
        float acc = 0.0f;
#pragma unroll
        for (int k = 0; k < D; ++k) {
            const float xk = __shfl(xo, k, 64);
            acc = fmaf(xk, Wl[k * D + lane], acc);
        }
        const float r  = acc * dinv[row];
        const float rn = __shfl_down(r, 1, 64);
        if (!(lane & 1))
            ybf[(size_t)row * 32 + (lane >> 1)] = pk_bf16(r, rn);
    }
}

// ---------------------------------------------------------------------------
// pull: h[n] = LeakyReLU(dinv[n]*(y[n] + sum_in y[s]) + b); fused BN stats.
// half-wave per neighbor: lanes 0-31 = edge a, 32-63 = edge b; lane holds 2 features.
__global__ void k_pull(const int* __restrict__ rp, const int* __restrict__ colbuf,
                       const unsigned* __restrict__ ybf, const float* __restrict__ dinv,
                       const float* __restrict__ b, float* __restrict__ h,
                       float* __restrict__ stats, int N) {
    const int lane = threadIdx.x & 63;
    const int sl   = lane & 31;
    const int hw   = lane >> 5;
    const int wib  = threadIdx.x >> 6;
    const float bx = b[2 * sl];
    const float by = b[2 * sl + 1];
    float s1x = 0.f, s1y = 0.f, s2x = 0.f, s2y = 0.f;

    for (int n = blockIdx.x * 4 + wib; n < N; n += gridDim.x * 4) {
        const int start = rp[n];
        const int end   = rp[n + 1];
        float ax = 0.f, ay = 0.f;
        if (hw == 0) {                                  // self term (once)
            const unsigned u = ybf[(size_t)n * 32 + sl];
            ax = bf_lo(u); ay = bf_hi(u);
        }
        for (int j = start; j < end; j += 64) {
            const int rem = end - j;
            const int cn  = rem < 64 ? rem : 64;
            const int ci  = (lane < cn) ? colbuf[j + lane] : 0;
            const int full = cn >> 1;
#pragma unroll 4
            for (int t = 0; t < full; ++t) {
                const int idx = __shfl(ci, 2 * t + hw, 64);
                const unsigned u = ybf[(size_t)idx * 32 + sl];
                ax += bf_lo(u); ay += bf_hi(u);
            }
            if (cn & 1) {
                const int idx = __shfl(ci, cn - 1, 64);
                if (hw == 0) {
                    const unsigned u = ybf[(size_t)idx * 32 + sl];
                    ax += bf_lo(u); ay += bf_hi(u);
                }
            }
        }
        // fold the two half-wave partial sums
        ax += __shfl_xor(ax, 32, 64);
        ay += __shfl_xor(ay, 32, 64);

        const float di = dinv[n];
        float vx = fmaf(di, ax, bx);
        float vy = fmaf(di, ay, by);
        vx = vx > 0.f ? vx : SLOPE * vx;
        vy = vy > 0.f ? vy : SLOPE * vy;
        if (hw == 0) {
            *(float2*)&h[(size_t)n * D + 2 * sl] = make_float2(vx, vy);
            s1x += vx; s1y += vy;
            s2x += vx * vx; s2y += vy * vy;
        }
    }

    __shared__ float r1x[256], r1y[256], r2x[256], r2y[256];
    const int tid = threadIdx.x;
    r1x[tid] = s1x; r1y[tid] = s1y; r2x[tid] = s2x; r2y[tid] = s2y;
    __syncthreads();
    if (tid < 32) {
        float a = 0.f, bsum = 0.f, c = 0.f, d = 0.f;
#pragma unroll
        for (int k = 0; k < 8; ++k) {
            a += r1x[tid + 32 * k];
            bsum += r1y[tid + 32 * k];
            c += r2x[tid + 32 * k];
            d += r2y[tid + 32 * k];
        }
        atomicAdd(&stats[2 * tid],     a);
        atomicAdd(&stats[2 * tid + 1], bsum);
        atomicAdd(&stats[64 + 2 * tid],     c);
        atomicAdd(&stats[64 + 2 * tid + 1], d);
    }
}

// ---------------------------------------------------------------------------
__global__ void k_finalize(const float* __restrict__ stats, const float* __restrict__ gamma,
                           const float* __restrict__ beta, float* __restrict__ ss, float invN) {
    const int t = threadIdx.x;
    const float mu  = stats[t] * invN;
    const float var = stats[64 + t] * invN - mu * mu;
    const float sc  = gamma[t] * rsqrtf(var + BN_EPS);
    ss[t]      = sc;
    ss[64 + t] = beta[t] - mu * sc;
}

__global__ void k_normalize(const float* __restrict__ h, const float* __restrict__ ss,
                            float* __restrict__ out, int total) {
    const int col = threadIdx.x & 63;
    const float sc = ss[col];
    const float sh = ss[64 + col];
    for (int i = blockIdx.x * blockDim.x + threadIdx.x; i < total; i += gridDim.x * blockDim.x)
        out[i] = fmaf(sc, h[i], sh);
}

// ---------------------------------------------------------------------------
extern "C" void kernel_launch(void* const* d_in, const int* in_sizes, int n_in,
                              void* d_out, int out_size, void* d_ws, size_t ws_size,
                              hipStream_t stream) {
    const float* x0     = (const float*)d_in[0];
    const int*   ei     = (const int*)d_in[1];
    const float* Ws     = (const float*)d_in[2];
    const float* bs     = (const float*)d_in[3];
    const float* gammas = (const float*)d_in[4];
    const float* betas  = (const float*)d_in[5];

    const int N = in_sizes[0] / D;
    const int E = in_sizes[1] / 2;
    const int L = in_sizes[2] / (D * D);

    const int* srcp = ei;
    const int* dstp = ei + E;

    char* wsb = (char*)d_ws;
    size_t o = 0;
    auto alloc = [&](size_t elems) { size_t r = o; o += (elems + 255) & ~(size_t)255; return r; };
    const size_t o_cnt   = alloc((size_t)N);          // int, zeroed
    const size_t o_cur   = alloc((size_t)N);          // int, zeroed
    const size_t o_stats = alloc((size_t)L * 128);    // float, zeroed
    const size_t zero_end = o;
    const size_t o_ss    = alloc((size_t)L * 128);    // float
    const size_t o_dinv  = alloc((size_t)N);          // float
    const size_t o_rp    = alloc((size_t)N + 1);      // int
    const size_t o_bsum  = alloc(512);                // int
    const size_t o_col   = alloc((size_t)E);          // int
    const size_t o_y     = alloc((size_t)N * 32);     // uint (bf16x2 packed)
    const size_t o_h     = alloc((size_t)N * D);      // float

    int*      cnt   = (int*)(wsb + o_cnt * 4);
    int*      cur   = (int*)(wsb + o_cur * 4);
    float*    stats = (float*)(wsb + o_stats * 4);
    float*    ss    = (float*)(wsb + o_ss * 4);
    float*    dinv  = (float*)(wsb + o_dinv * 4);
    int*      rp    = (int*)(wsb + o_rp * 4);
    int*      bsum  = (int*)(wsb + o_bsum * 4);
    int*      col   = (int*)(wsb + o_col * 4);
    unsigned* ybf   = (unsigned*)(wsb + o_y * 4);
    float*    h     = (float*)(wsb + o_h * 4);
    float*    out   = (float*)d_out;

    hipMemsetAsync(d_ws, 0, zero_end * 4, stream);

    k_count<<<1024, 256, 0, stream>>>(dstp, cnt, E);
    k_dinv<<<512, 256, 0, stream>>>(cnt, dinv, N);
    const int B = (N + 255) / 256;
    k_scan1<<<B, 256, 0, stream>>>(cnt, rp, bsum, N);
    k_scan2<<<1, 512, 0, stream>>>(bsum, rp, B, E, N);
    k_scan3<<<B, 256, 0, stream>>>(rp, bsum, N);
    k_scatter<<<1024, 256, 0, stream>>>(srcp, dstp, rp, cur, col, E);

    const float invN = 1.0f / (float)N;
    const float* xin = x0;
    for (int l = 0; l < L; ++l) {
        const float* Wl = Ws + (size_t)l * D * D;
        const float* bl = bs + (size_t)l * D;
        if (l == 0)
            k_gemm<false><<<1024, 256, 0, stream>>>(xin, Wl, nullptr, dinv, ybf, N);
        else
            k_gemm<true><<<1024, 256, 0, stream>>>(xin, Wl, ss + (size_t)(l - 1) * 128, dinv, ybf, N);
        k_pull<<<2048, 256, 0, stream>>>(rp, col, ybf, dinv, bl, h, stats + (size_t)l * 128, N);
        k_finalize<<<1, 64, 0, stream>>>(stats + (size_t)l * 128, gammas + (size_t)l * D,
                                         betas + (size_t)l * D, ss + (size_t)l * 128, invN);
        xin = h;
    }
    k_normalize<<<1024, 256, 0, stream>>>(h, ss + (size_t)(L - 1) * 128, out, N * D);
}

// Round 4
// 543.952 us; speedup vs baseline: 1.4587x; 1.4587x over previous
//
#include <hip/hip_runtime.h>

#define D 64
#define SLOPE 0.2f
#define BN_EPS 1e-5f

// bf16 pack/unpack (RNE)
static __device__ __forceinline__ unsigned pk_bf16(float fx, float fy) {
    unsigned bx = __float_as_uint(fx);
    unsigned by = __float_as_uint(fy);
    bx = (bx + 0x7fffu + ((bx >> 16) & 1u)) >> 16;
    by = (by + 0x7fffu + ((by >> 16) & 1u)) & 0xffff0000u;
    return bx | by;
}
static __device__ __forceinline__ float bf_lo(unsigned u) { return __uint_as_float(u << 16); }
static __device__ __forceinline__ float bf_hi(unsigned u) { return __uint_as_float(u & 0xffff0000u); }

// ---------------------------------------------------------------------------
// CSR build
__global__ void k_count(const int* __restrict__ dst, int* __restrict__ cnt, int E) {
    for (int e = blockIdx.x * blockDim.x + threadIdx.x; e < E; e += gridDim.x * blockDim.x)
        atomicAdd(&cnt[dst[e]], 1);
}

// scan1 also produces dinv = rsqrt(cnt+1)
__global__ void k_scan1(const int* __restrict__ cnt, int* __restrict__ rp,
                        int* __restrict__ bsum, float* __restrict__ dinv, int N) {
    __shared__ int l[256];
    const int t = threadIdx.x;
    const int i = blockIdx.x * 256 + t;
    const int v = (i < N) ? cnt[i] : 0;
    l[t] = v;
    __syncthreads();
    for (int off = 1; off < 256; off <<= 1) {
        int x = l[t];
        if (t >= off) x += l[t - off];
        __syncthreads();
        l[t] = x;
        __syncthreads();
    }
    if (i < N) {
        rp[i] = l[t] - v;
        dinv[i] = rsqrtf((float)v + 1.0f);
    }
    if (t == 255) bsum[blockIdx.x] = l[255];
}

__global__ void k_scan2(int* __restrict__ bsum, int* __restrict__ rp, int B, int E, int N) {
    __shared__ int l[512];
    const int t = threadIdx.x;
    const int v = (t < B) ? bsum[t] : 0;
    l[t] = v;
    __syncthreads();
    for (int off = 1; off < 512; off <<= 1) {
        int x = l[t];
        if (t >= off) x += l[t - off];
        __syncthreads();
        l[t] = x;
        __syncthreads();
    }
    if (t < B) bsum[t] = l[t] - v;
    if (t == 0) rp[N] = E;
}

__global__ void k_scan3(int* __restrict__ rp, const int* __restrict__ bsum, int N) {
    const int i = blockIdx.x * blockDim.x + threadIdx.x;
    if (i < N) rp[i] += bsum[i >> 8];
}

__global__ void k_scatter(const int* __restrict__ src, const int* __restrict__ dst,
                          const int* __restrict__ rp, int* __restrict__ cur,
                          int* __restrict__ colbuf, int E) {
    for (int e = blockIdx.x * blockDim.x + threadIdx.x; e < E; e += gridDim.x * blockDim.x) {
        const int d = dst[e];
        const int pos = rp[d] + atomicAdd(&cur[d], 1);
        colbuf[pos] = src[e];
    }
}

// ---------------------------------------------------------------------------
// Per-layer prep: fold BN affine of previous layer into W.
// W'[k][c] = sc[k]*W[k][c];  bvec[c] = sum_k sh[k]*W[k][c]
__global__ void k_prep(const float* __restrict__ W, const float* __restrict__ stats,
                       const float* __restrict__ gamma, const float* __restrict__ beta,
                       float* __restrict__ Wp, float* __restrict__ bvec,
                       float invN, int affine) {
    __shared__ float scs[D], shs[D];
    const int t = threadIdx.x;
    if (t < D) {
        float sc = 1.0f, sh = 0.0f;
        if (affine) {
            const float mu  = stats[t] * invN;
            const float var = stats[D + t] * invN - mu * mu;
            sc = gamma[t] * rsqrtf(var + BN_EPS);
            sh = beta[t] - mu * sc;
        }
        scs[t] = sc; shs[t] = sh;
    }
    __syncthreads();
    for (int i = t; i < D * D; i += blockDim.x)
        Wp[i] = scs[i >> 6] * W[i];
    if (t < D) {
        float s = 0.0f;
#pragma unroll
        for (int k = 0; k < D; ++k) s += shs[k] * W[k * D + t];
        bvec[t] = s;
    }
}

// ---------------------------------------------------------------------------
// ybf[row] = pack_bf16( (x @ W' + bvec) * dinv[row] )
// W' column held in 64 VGPRs per lane; x-row loads are wave-uniform (scalarizable).
__global__ __launch_bounds__(256) void k_gemm(const float* __restrict__ x,
                                              const float* __restrict__ Wp,
                                              const float* __restrict__ bvec,
                                              const float* __restrict__ dinv,
                                              unsigned* __restrict__ ybf, int N) {
    const int lane = threadIdx.x & 63;
    const int wib  = threadIdx.x >> 6;
    float Wreg[D];
#pragma unroll
    for (int k = 0; k < D; ++k) Wreg[k] = Wp[k * D + lane];
    const float bv = bvec[lane];
    const int stride = gridDim.x * 4;

    for (int row = __builtin_amdgcn_readfirstlane(blockIdx.x * 4 + wib); row < N; row += stride) {
        const float4* xr = (const float4*)(x + (size_t)row * D);
        float acc = 0.0f;
#pragma unroll
        for (int k4 = 0; k4 < 16; ++k4) {
            const float4 xv = xr[k4];
            acc = fmaf(xv.x, Wreg[4 * k4 + 0], acc);
            acc = fmaf(xv.y, Wreg[4 * k4 + 1], acc);
            acc = fmaf(xv.z, Wreg[4 * k4 + 2], acc);
            acc = fmaf(xv.w, Wreg[4 * k4 + 3], acc);
        }
        const float r  = (acc + bv) * dinv[row];
        const float rn = __shfl_down(r, 1, 64);
        if (!(lane & 1))
            ybf[(size_t)row * 32 + (lane >> 1)] = pk_bf16(r, rn);
    }
}

// ---------------------------------------------------------------------------
// pull: quarter-wave per edge, uint2 per lane (4 bf16 features), 4 independent chains.
// h[n] = LeakyReLU(dinv[n]*(y[n] + sum_in y[s]) + b); fused BN stats.
__global__ __launch_bounds__(256) void k_pull(const int* __restrict__ rp,
                                              const int* __restrict__ colbuf,
                                              const uint2* __restrict__ ybf2,
                                              const float* __restrict__ dinv,
                                              const float* __restrict__ b,
                                              float* __restrict__ h,
                                              float* __restrict__ stats, int N) {
    const int lane = threadIdx.x & 63;
    const int sl   = lane & 15;          // slot within row (uint2 granularity)
    const int qw   = lane >> 4;          // quarter-wave 0..3
    const int wib  = threadIdx.x >> 6;
    const float4 bb = *(const float4*)&b[4 * sl];
    float s1[4] = {0.f, 0.f, 0.f, 0.f}, s2[4] = {0.f, 0.f, 0.f, 0.f};

    for (int n = blockIdx.x * 4 + wib; n < N; n += gridDim.x * 4) {
        const int start = rp[n];
        const int end   = rp[n + 1];
        float a[4][4];
#pragma unroll
        for (int c = 0; c < 4; ++c)
#pragma unroll
            for (int f = 0; f < 4; ++f) a[c][f] = 0.f;

        if (qw == 0) {                   // self term
            const uint2 u = ybf2[(size_t)n * 16 + sl];
            a[0][0] += bf_lo(u.x); a[0][1] += bf_hi(u.x);
            a[0][2] += bf_lo(u.y); a[0][3] += bf_hi(u.y);
        }

        for (int j = start; j < end; j += 64) {
            const int rem = end - j;
            const int cn  = rem < 64 ? rem : 64;
            const int ci  = (lane < cn) ? colbuf[j + lane] : 0;
            for (int s = 0; 16 * s < cn; ++s) {
#pragma unroll
                for (int c = 0; c < 4; ++c) {
                    const int e   = 16 * s + 4 * c + qw;
                    const int idx = __shfl(ci, e, 64);
                    uint2 u = ybf2[(size_t)idx * 16 + sl];
                    const bool val = e < cn;
                    u.x = val ? u.x : 0u;
                    u.y = val ? u.y : 0u;
                    a[c][0] += bf_lo(u.x); a[c][1] += bf_hi(u.x);
                    a[c][2] += bf_lo(u.y); a[c][3] += bf_hi(u.y);
                }
            }
        }

        float v[4];
#pragma unroll
        for (int f = 0; f < 4; ++f) {
            v[f] = (a[0][f] + a[1][f]) + (a[2][f] + a[3][f]);
            v[f] += __shfl_xor(v[f], 16, 64);
            v[f] += __shfl_xor(v[f], 32, 64);
        }

        if (qw == 0) {
            const float di = dinv[n];
            float4 hv;
            float* hp = &hv.x;
            const float* bp = &bb.x;
#pragma unroll
            for (int f = 0; f < 4; ++f) {
                float t = fmaf(di, v[f], bp[f]);
                t = t > 0.f ? t : SLOPE * t;
                hp[f] = t;
                s1[f] += t;
                s2[f] += t * t;
            }
            *(float4*)&h[(size_t)n * D + 4 * sl] = hv;
        }
    }

    __shared__ float s1d[4][16][4], s2d[4][16][4];
    if (qw == 0) {
#pragma unroll
        for (int f = 0; f < 4; ++f) { s1d[wib][sl][f] = s1[f]; s2d[wib][sl][f] = s2[f]; }
    }
    __syncthreads();
    const int tid = threadIdx.x;
    if (tid < 64) {
        const int ssl = tid >> 2, f = tid & 3;
        const float A = (s1d[0][ssl][f] + s1d[1][ssl][f]) + (s1d[2][ssl][f] + s1d[3][ssl][f]);
        const float B = (s2d[0][ssl][f] + s2d[1][ssl][f]) + (s2d[2][ssl][f] + s2d[3][ssl][f]);
        atomicAdd(&stats[tid], A);
        atomicAdd(&stats[64 + tid], B);
    }
}

// ---------------------------------------------------------------------------
// out = sc*h + sh, sc/sh computed inline from stats
__global__ void k_normalize(const float* __restrict__ h, const float* __restrict__ stats,
                            const float* __restrict__ gamma, const float* __restrict__ beta,
                            float* __restrict__ out, float invN, int total) {
    const int col = threadIdx.x & 63;
    const float mu  = stats[col] * invN;
    const float var = stats[64 + col] * invN - mu * mu;
    const float sc  = gamma[col] * rsqrtf(var + BN_EPS);
    const float sh  = beta[col] - mu * sc;
    for (int i = blockIdx.x * blockDim.x + threadIdx.x; i < total; i += gridDim.x * blockDim.x)
        out[i] = fmaf(sc, h[i], sh);
}

// ---------------------------------------------------------------------------
extern "C" void kernel_launch(void* const* d_in, const int* in_sizes, int n_in,
                              void* d_out, int out_size, void* d_ws, size_t ws_size,
                              hipStream_t stream) {
    const float* x0     = (const float*)d_in[0];
    const int*   ei     = (const int*)d_in[1];
    const float* Ws     = (const float*)d_in[2];
    const float* bs     = (const float*)d_in[3];
    const float* gammas = (const float*)d_in[4];
    const float* betas  = (const float*)d_in[5];

    const int N = in_sizes[0] / D;
    const int E = in_sizes[1] / 2;
    const int L = in_sizes[2] / (D * D);

    const int* srcp = ei;
    const int* dstp = ei + E;

    char* wsb = (char*)d_ws;
    size_t o = 0;
    auto alloc = [&](size_t elems) { size_t r = o; o += (elems + 255) & ~(size_t)255; return r; };
    const size_t o_cnt   = alloc((size_t)N);          // int, zeroed
    const size_t o_cur   = alloc((size_t)N);          // int, zeroed
    const size_t o_stats = alloc((size_t)L * 128);    // float, zeroed
    const size_t zero_end = o;
    const size_t o_dinv  = alloc((size_t)N);          // float
    const size_t o_rp    = alloc((size_t)N + 1);      // int
    const size_t o_bsum  = alloc(512);                // int
    const size_t o_col   = alloc((size_t)E);          // int
    const size_t o_wp    = alloc((size_t)D * D);      // float (folded W)
    const size_t o_bvec  = alloc((size_t)D);          // float
    const size_t o_y     = alloc((size_t)N * 32);     // uint (bf16x2 packed)
    const size_t o_h     = alloc((size_t)N * D);      // float

    int*      cnt   = (int*)(wsb + o_cnt * 4);
    int*      cur   = (int*)(wsb + o_cur * 4);
    float*    stats = (float*)(wsb + o_stats * 4);
    float*    dinv  = (float*)(wsb + o_dinv * 4);
    int*      rp    = (int*)(wsb + o_rp * 4);
    int*      bsum  = (int*)(wsb + o_bsum * 4);
    int*      col   = (int*)(wsb + o_col * 4);
    float*    Wp    = (float*)(wsb + o_wp * 4);
    float*    bvec  = (float*)(wsb + o_bvec * 4);
    unsigned* ybf   = (unsigned*)(wsb + o_y * 4);
    float*    h     = (float*)(wsb + o_h * 4);
    float*    out   = (float*)d_out;

    hipMemsetAsync(d_ws, 0, zero_end * 4, stream);

    k_count<<<1024, 256, 0, stream>>>(dstp, cnt, E);
    const int B = (N + 255) / 256;
    k_scan1<<<B, 256, 0, stream>>>(cnt, rp, bsum, dinv, N);
    k_scan2<<<1, 512, 0, stream>>>(bsum, rp, B, E, N);
    k_scan3<<<B, 256, 0, stream>>>(rp, bsum, N);
    k_scatter<<<1024, 256, 0, stream>>>(srcp, dstp, rp, cur, col, E);

    const float invN = 1.0f / (float)N;
    const float* xin = x0;
    for (int l = 0; l < L; ++l) {
        const float* Wl = Ws + (size_t)l * D * D;
        const float* bl = bs + (size_t)l * D;
        k_prep<<<1, 256, 0, stream>>>(Wl, stats + (size_t)(l ? l - 1 : 0) * 128,
                                      gammas + (size_t)(l ? l - 1 : 0) * D,
                                      betas + (size_t)(l ? l - 1 : 0) * D,
                                      Wp, bvec, invN, l > 0 ? 1 : 0);
        k_gemm<<<1024, 256, 0, stream>>>(xin, Wp, bvec, dinv, ybf, N);
        k_pull<<<2048, 256, 0, stream>>>(rp, col, (const uint2*)ybf, dinv, bl, h,
                                         stats + (size_t)l * 128, N);
        xin = h;
    }
    k_normalize<<<1024, 256, 0, stream>>>(h, stats + (size_t)(L - 1) * 128,
                                          gammas + (size_t)(L - 1) * D,
                                          betas + (size_t)(L - 1) * D, out, invN, N * D);
}

// Round 5
// 424.074 us; speedup vs baseline: 1.8710x; 1.2827x over previous
//
#include <hip/hip_runtime.h>

#define D 64
#define SLOPE 0.2f
#define BN_EPS 1e-5f
#define BSHIFT 9                 // 512 nodes per bucket
#define CHUNK 7168               // edges staged in LDS per partition block (56KB)

// bf16 pack/unpack (RNE)
static __device__ __forceinline__ unsigned pk_bf16(float fx, float fy) {
    unsigned bx = __float_as_uint(fx);
    unsigned by = __float_as_uint(fy);
    bx = (bx + 0x7fffu + ((bx >> 16) & 1u)) >> 16;
    by = (by + 0x7fffu + ((by >> 16) & 1u)) & 0xffff0000u;
    return bx | by;
}
static __device__ __forceinline__ float bf_lo(unsigned u) { return __uint_as_float(u << 16); }
static __device__ __forceinline__ float bf_hi(unsigned u) { return __uint_as_float(u & 0xffff0000u); }

// ---------------------------------------------------------------------------
// Bucket histogram: LDS-aggregated, 196 global atomics per block.
__global__ __launch_bounds__(256) void k_hist(const int* __restrict__ dst,
                                              int* __restrict__ bcnt, int E, int NB) {
    __shared__ int hist[256];
    for (int i = threadIdx.x; i < NB; i += 256) hist[i] = 0;
    __syncthreads();
    for (int e = blockIdx.x * 256 + threadIdx.x; e < E; e += gridDim.x * 256)
        atomicAdd(&hist[dst[e] >> BSHIFT], 1);
    __syncthreads();
    for (int i = threadIdx.x; i < NB; i += 256)
        if (hist[i]) atomicAdd(&bcnt[i], hist[i]);
}

// Single-block exclusive scan of bucket counts; init partition cursors.
__global__ __launch_bounds__(256) void k_bscan(const int* __restrict__ bcnt,
                                               int* __restrict__ bbase, int* __restrict__ pcur,
                                               int* __restrict__ rp, int NB, int E, int N) {
    __shared__ int l[256];
    const int t = threadIdx.x;
    const int v = (t < NB) ? bcnt[t] : 0;
    l[t] = v;
    __syncthreads();
    for (int off = 1; off < 256; off <<= 1) {
        int x = l[t];
        if (t >= off) x += l[t - off];
        __syncthreads();
        l[t] = x;
        __syncthreads();
    }
    if (t < NB) {
        const int excl = l[t] - v;
        bbase[t] = excl;
        pcur[t]  = excl;
    }
    if (t == 0) { bbase[NB] = E; rp[N] = E; }
}

// LDS radix-partition: stage a chunk, group by bucket, write grouped runs to arena.
__global__ __launch_bounds__(256) void k_part(const int* __restrict__ src,
                                              const int* __restrict__ dst,
                                              int* __restrict__ pcur,
                                              uint2* __restrict__ arena,
                                              int E, int NB, int nchunks) {
    __shared__ uint2 stage[CHUNK];
    __shared__ int hist[256], lofs[256], gbase[256];

    for (int chunk = blockIdx.x; chunk < nchunks; chunk += gridDim.x) {
        const int e0 = chunk * CHUNK;
        const int cn = min(CHUNK, E - e0);

        for (int i = threadIdx.x; i < NB; i += 256) hist[i] = 0;
        __syncthreads();
        for (int i = threadIdx.x; i < cn; i += 256)
            atomicAdd(&hist[dst[e0 + i] >> BSHIFT], 1);
        __syncthreads();

        // exclusive scan of hist -> lofs; reserve global ranges
        {
            const int t = threadIdx.x;
            const int v = (t < NB) ? hist[t] : 0;
            l_scan:
            lofs[t] = v;
            __syncthreads();
            for (int off = 1; off < 256; off <<= 1) {
                int x = lofs[t];
                if (t >= off) x += lofs[t - off];
                __syncthreads();
                lofs[t] = x;
                __syncthreads();
            }
            const int excl = lofs[t] - v;
            __syncthreads();
            lofs[t] = excl;
            if (t < NB && v > 0) gbase[t] = atomicAdd(&pcur[t], v);
            __syncthreads();
        }

        // place edges grouped into LDS stage (lofs becomes per-bucket end)
        for (int i = threadIdx.x; i < cn; i += 256) {
            const int d = dst[e0 + i];
            const int s = src[e0 + i];
            const int b = d >> BSHIFT;
            const int p = atomicAdd(&lofs[b], 1);
            stage[p] = make_uint2((unsigned)s, (unsigned)d);
        }
        __syncthreads();

        // copy grouped runs to arena (coalesced: consecutive i mostly same bucket)
        for (int i = threadIdx.x; i < cn; i += 256) {
            const uint2 u = stage[i];
            const int b = (int)(u.y >> BSHIFT);
            const int startb = lofs[b] - hist[b];
            arena[gbase[b] + (i - startb)] = u;
        }
        __syncthreads();
    }
}

// Per-bucket: per-node counts (LDS), 512-scan -> rp + dinv, scatter colbuf locally.
__global__ __launch_bounds__(512) void k_build(const uint2* __restrict__ arena,
                                               const int* __restrict__ bbase,
                                               int* __restrict__ rp, int* __restrict__ colbuf,
                                               float* __restrict__ dinv, int N) {
    const int b = blockIdx.x;
    const int nbase = b << BSHIFT;
    const int nlocal = min(1 << BSHIFT, N - nbase);
    const int abeg = bbase[b];
    const int aend = bbase[b + 1];
    __shared__ int ncnt[512], sc[512], lcur[512];
    const int t = threadIdx.x;

    ncnt[t] = 0;
    __syncthreads();
    for (int i = abeg + t; i < aend; i += 512)
        atomicAdd(&ncnt[(int)(arena[i].y) - nbase], 1);
    __syncthreads();

    const int v = ncnt[t];
    sc[t] = v;
    __syncthreads();
    for (int off = 1; off < 512; off <<= 1) {
        int x = sc[t];
        if (t >= off) x += sc[t - off];
        __syncthreads();
        sc[t] = x;
        __syncthreads();
    }
    const int excl = sc[t] - v;
    lcur[t] = excl;
    if (t < nlocal) {
        rp[nbase + t]   = abeg + excl;
        dinv[nbase + t] = rsqrtf((float)v + 1.0f);
    }
    __syncthreads();

    for (int i = abeg + t; i < aend; i += 512) {
        const uint2 u = arena[i];
        const int ln = (int)u.y - nbase;
        const int p = atomicAdd(&lcur[ln], 1);
        colbuf[abeg + p] = (int)u.x;
    }
}

// ---------------------------------------------------------------------------
// Per-layer prep: fold BN affine of previous layer into W.
__global__ void k_prep(const float* __restrict__ W, const float* __restrict__ stats,
                       const float* __restrict__ gamma, const float* __restrict__ beta,
                       float* __restrict__ Wp, float* __restrict__ bvec,
                       float invN, int affine) {
    __shared__ float scs[D], shs[D];
    const int t = threadIdx.x;
    if (t < D) {
        float sc = 1.0f, sh = 0.0f;
        if (affine) {
            const float mu  = stats[t] * invN;
            const float var = stats[D + t] * invN - mu * mu;
            sc = gamma[t] * rsqrtf(var + BN_EPS);
            sh = beta[t] - mu * sc;
        }
        scs[t] = sc; shs[t] = sh;
    }
    __syncthreads();
    for (int i = t; i < D * D; i += blockDim.x)
        Wp[i] = scs[i >> 6] * W[i];
    if (t < D) {
        float s = 0.0f;
#pragma unroll
        for (int k = 0; k < D; ++k) s += shs[k] * W[k * D + t];
        bvec[t] = s;
    }
}

// ---------------------------------------------------------------------------
// ybf[row] = pack_bf16( (x @ W' + bvec) * dinv[row] )
__global__ __launch_bounds__(256) void k_gemm(const float* __restrict__ x,
                                              const float* __restrict__ Wp,
                                              const float* __restrict__ bvec,
                                              const float* __restrict__ dinv,
                                              unsigned* __restrict__ ybf, int N) {
    const int lane = threadIdx.x & 63;
    const int wib  = threadIdx.x >> 6;
    float Wreg[D];
#pragma unroll
    for (int k = 0; k < D; ++k) Wreg[k] = Wp[k * D + lane];
    const float bv = bvec[lane];
    const int stride = gridDim.x * 4;

    for (int row = __builtin_amdgcn_readfirstlane(blockIdx.x * 4 + wib); row < N; row += stride) {
        const float4* xr = (const float4*)(x + (size_t)row * D);
        float acc = 0.0f;
#pragma unroll
        for (int k4 = 0; k4 < 16; ++k4) {
            const float4 xv = xr[k4];
            acc = fmaf(xv.x, Wreg[4 * k4 + 0], acc);
            acc = fmaf(xv.y, Wreg[4 * k4 + 1], acc);
            acc = fmaf(xv.z, Wreg[4 * k4 + 2], acc);
            acc = fmaf(xv.w, Wreg[4 * k4 + 3], acc);
        }
        const float r  = (acc + bv) * dinv[row];
        const float rn = __shfl_down(r, 1, 64);
        if (!(lane & 1))
            ybf[(size_t)row * 32 + (lane >> 1)] = pk_bf16(r, rn);
    }
}

// ---------------------------------------------------------------------------
// pull: node PAIR per wave iteration. Combined colbuf segment [rp[n0], rp[n0+2]).
// a = sum of all valid edges (+ self terms); bacc = sum of node1 edges (+ self1).
// node0 = a - bacc, node1 = bacc.  Quarter-wave qw0 finishes n0, qw1 finishes n1.
__global__ __launch_bounds__(256) void k_pull(const int* __restrict__ rp,
                                              const int* __restrict__ colbuf,
                                              const uint2* __restrict__ ybf2,
                                              const float* __restrict__ dinv,
                                              const float* __restrict__ bvecin,
                                              float* __restrict__ h,
                                              float* __restrict__ stats, int N) {
    const int lane = threadIdx.x & 63;
    const int sl   = lane & 15;
    const int qw   = lane >> 4;
    const int wib  = threadIdx.x >> 6;
    const float4 bb = *(const float4*)&bvecin[4 * sl];
    const float* bp = &bb.x;
    float s1[4] = {0.f, 0.f, 0.f, 0.f}, s2[4] = {0.f, 0.f, 0.f, 0.f};

    const int wid = blockIdx.x * 4 + wib;
    const int wstride = gridDim.x * 4;

    for (int n0 = wid * 2; n0 < N; n0 += wstride * 2) {
        const int n1 = n0 + 1;
        const bool has1 = n1 < N;
        const int2 r01 = *(const int2*)&rp[n0];
        const int start = r01.x;
        const int mid   = r01.y;
        const int end   = has1 ? rp[n0 + 2] : r01.y;

        float a[4][4], ba[4][4];
#pragma unroll
        for (int c = 0; c < 4; ++c)
#pragma unroll
            for (int f = 0; f < 4; ++f) { a[c][f] = 0.f; ba[c][f] = 0.f; }

        if (qw == 0) {                       // self term node0 -> a only
            const uint2 u = ybf2[(size_t)n0 * 16 + sl];
            a[0][0] += bf_lo(u.x); a[0][1] += bf_hi(u.x);
            a[0][2] += bf_lo(u.y); a[0][3] += bf_hi(u.y);
        } else if (qw == 1 && has1) {        // self term node1 -> a and bacc
            const uint2 u = ybf2[(size_t)n1 * 16 + sl];
            const float f0 = bf_lo(u.x), f1 = bf_hi(u.x), f2 = bf_lo(u.y), f3 = bf_hi(u.y);
            a[0][0] += f0; a[0][1] += f1; a[0][2] += f2; a[0][3] += f3;
            ba[0][0] += f0; ba[0][1] += f1; ba[0][2] += f2; ba[0][3] += f3;
        }

        for (int j = start; j < end; j += 64) {
            const int rem = end - j;
            const int cn  = rem < 64 ? rem : 64;
            const int ci  = (lane < cn) ? colbuf[j + lane] : 0;
            for (int s = 0; 16 * s < cn; ++s) {
#pragma unroll
                for (int c = 0; c < 4; ++c) {
                    const int e   = 16 * s + 4 * c + qw;
                    const int idx = __shfl(ci, e, 64);
                    uint2 u = ybf2[(size_t)idx * 16 + sl];
                    const bool val = e < cn;
                    const bool is1 = (j + e) >= mid;
                    u.x = val ? u.x : 0u;
                    u.y = val ? u.y : 0u;
                    const float f0 = bf_lo(u.x), f1 = bf_hi(u.x);
                    const float f2 = bf_lo(u.y), f3 = bf_hi(u.y);
                    a[c][0] += f0; a[c][1] += f1; a[c][2] += f2; a[c][3] += f3;
                    ba[c][0] += is1 ? f0 : 0.f;
                    ba[c][1] += is1 ? f1 : 0.f;
                    ba[c][2] += is1 ? f2 : 0.f;
                    ba[c][3] += is1 ? f3 : 0.f;
                }
            }
        }

        float vA[4], vB[4];
#pragma unroll
        for (int f = 0; f < 4; ++f) {
            vA[f] = (a[0][f] + a[1][f]) + (a[2][f] + a[3][f]);
            vA[f] += __shfl_xor(vA[f], 16, 64);
            vA[f] += __shfl_xor(vA[f], 32, 64);
            vB[f] = (ba[0][f] + ba[1][f]) + (ba[2][f] + ba[3][f]);
            vB[f] += __shfl_xor(vB[f], 16, 64);
            vB[f] += __shfl_xor(vB[f], 32, 64);
        }

        if (qw == 0) {
            const float di = dinv[n0];
            float4 hv; float* hp = &hv.x;
#pragma unroll
            for (int f = 0; f < 4; ++f) {
                float t = fmaf(di, vA[f] - vB[f], bp[f]);
                t = t > 0.f ? t : SLOPE * t;
                hp[f] = t; s1[f] += t; s2[f] += t * t;
            }
            *(float4*)&h[(size_t)n0 * D + 4 * sl] = hv;
        } else if (qw == 1 && has1) {
            const float di = dinv[n1];
            float4 hv; float* hp = &hv.x;
#pragma unroll
            for (int f = 0; f < 4; ++f) {
                float t = fmaf(di, vB[f], bp[f]);
                t = t > 0.f ? t : SLOPE * t;
                hp[f] = t; s1[f] += t; s2[f] += t * t;
            }
            *(float4*)&h[(size_t)n1 * D + 4 * sl] = hv;
        }
    }

    __shared__ float s1d[8][16][4], s2d[8][16][4];
    if (qw < 2) {
#pragma unroll
        for (int f = 0; f < 4; ++f) {
            s1d[wib * 2 + qw][sl][f] = s1[f];
            s2d[wib * 2 + qw][sl][f] = s2[f];
        }
    }
    __syncthreads();
    const int tid = threadIdx.x;
    if (tid < 64) {
        const int ssl = tid >> 2, f = tid & 3;
        float A = 0.f, B = 0.f;
#pragma unroll
        for (int g = 0; g < 8; ++g) { A += s1d[g][ssl][f]; B += s2d[g][ssl][f]; }
        atomicAdd(&stats[tid], A);
        atomicAdd(&stats[64 + tid], B);
    }
}

// ---------------------------------------------------------------------------
__global__ void k_normalize(const float* __restrict__ h, const float* __restrict__ stats,
                            const float* __restrict__ gamma, const float* __restrict__ beta,
                            float* __restrict__ out, float invN, int total) {
    const int col = threadIdx.x & 63;
    const float mu  = stats[col] * invN;
    const float var = stats[64 + col] * invN - mu * mu;
    const float sc  = gamma[col] * rsqrtf(var + BN_EPS);
    const float sh  = beta[col] - mu * sc;
    for (int i = blockIdx.x * blockDim.x + threadIdx.x; i < total; i += gridDim.x * blockDim.x)
        out[i] = fmaf(sc, h[i], sh);
}

// ---------------------------------------------------------------------------
extern "C" void kernel_launch(void* const* d_in, const int* in_sizes, int n_in,
                              void* d_out, int out_size, void* d_ws, size_t ws_size,
                              hipStream_t stream) {
    const float* x0     = (const float*)d_in[0];
    const int*   ei     = (const int*)d_in[1];
    const float* Ws     = (const float*)d_in[2];
    const float* bs     = (const float*)d_in[3];
    const float* gammas = (const float*)d_in[4];
    const float* betas  = (const float*)d_in[5];

    const int N = in_sizes[0] / D;
    const int E = in_sizes[1] / 2;
    const int L = in_sizes[2] / (D * D);
    const int NB = (N + (1 << BSHIFT) - 1) >> BSHIFT;      // <= 256
    const int nchunks = (E + CHUNK - 1) / CHUNK;

    const int* srcp = ei;
    const int* dstp = ei + E;

    char* wsb = (char*)d_ws;
    size_t o = 0;
    auto alloc = [&](size_t elems) { size_t r = o; o += (elems + 255) & ~(size_t)255; return r; };
    const size_t o_bcnt  = alloc(256);                // int, zeroed
    const size_t o_stats = alloc((size_t)L * 128);    // float, zeroed
    const size_t zero_end = o;
    const size_t o_bbase = alloc(257);                // int
    const size_t o_pcur  = alloc(256);                // int
    const size_t o_rp    = alloc((size_t)N + 1);      // int
    const size_t o_dinv  = alloc((size_t)N);          // float
    const size_t o_arena = alloc((size_t)E * 2);      // uint2
    const size_t o_col   = alloc((size_t)E);          // int
    const size_t o_wp    = alloc((size_t)D * D);      // float
    const size_t o_bvec  = alloc((size_t)D);          // float
    const size_t o_y     = alloc((size_t)N * 32);     // uint (bf16x2 packed)
    const size_t o_h     = alloc((size_t)N * D);      // float

    int*      bcnt  = (int*)(wsb + o_bcnt * 4);
    float*    stats = (float*)(wsb + o_stats * 4);
    int*      bbase = (int*)(wsb + o_bbase * 4);
    int*      pcur  = (int*)(wsb + o_pcur * 4);
    int*      rp    = (int*)(wsb + o_rp * 4);
    float*    dinv  = (float*)(wsb + o_dinv * 4);
    uint2*    arena = (uint2*)(wsb + o_arena * 4);
    int*      col   = (int*)(wsb + o_col * 4);
    float*    Wp    = (float*)(wsb + o_wp * 4);
    float*    bvec  = (float*)(wsb + o_bvec * 4);
    unsigned* ybf   = (unsigned*)(wsb + o_y * 4);
    float*    h     = (float*)(wsb + o_h * 4);
    float*    out   = (float*)d_out;

    hipMemsetAsync(d_ws, 0, zero_end * 4, stream);

    k_hist<<<512, 256, 0, stream>>>(dstp, bcnt, E, NB);
    k_bscan<<<1, 256, 0, stream>>>(bcnt, bbase, pcur, rp, NB, E, N);
    k_part<<<nchunks, 256, 0, stream>>>(srcp, dstp, pcur, arena, E, NB, nchunks);
    k_build<<<NB, 512, 0, stream>>>(arena, bbase, rp, col, dinv, N);

    const float invN = 1.0f / (float)N;
    const float* xin = x0;
    for (int l = 0; l < L; ++l) {
        const float* Wl = Ws + (size_t)l * D * D;
        const float* bl = bs + (size_t)l * D;
        k_prep<<<1, 256, 0, stream>>>(Wl, stats + (size_t)(l ? l - 1 : 0) * 128,
                                      gammas + (size_t)(l ? l - 1 : 0) * D,
                                      betas + (size_t)(l ? l - 1 : 0) * D,
                                      Wp, bvec, invN, l > 0 ? 1 : 0);
        k_gemm<<<1024, 256, 0, stream>>>(xin, Wp, bvec, dinv, ybf, N);
        k_pull<<<2048, 256, 0, stream>>>(rp, col, (const uint2*)ybf, dinv, bl, h,
                                         stats + (size_t)l * 128, N);
        xin = h;
    }
    k_normalize<<<1024, 256, 0, stream>>>(h, stats + (size_t)(L - 1) * 128,
                                          gammas + (size_t)(L - 1) * D,
                                          betas + (size_t)(L - 1) * D, out, invN, N * D);
}

// Round 7
// 407.328 us; speedup vs baseline: 1.9479x; 1.0411x over previous
//
#include <hip/hip_runtime.h>

#define D 64
#define SLOPE 0.2f
#define BN_EPS 1e-5f
#define BSHIFT 9                  // 512 nodes per bucket
#define BUCKET 512
#define CHUNK 8192                // edges per partition block

// bf16 pack/unpack (RNE)
static __device__ __forceinline__ unsigned pk_bf16(float fx, float fy) {
    unsigned bx = __float_as_uint(fx);
    unsigned by = __float_as_uint(fy);
    bx = (bx + 0x7fffu + ((bx >> 16) & 1u)) >> 16;
    by = (by + 0x7fffu + ((by >> 16) & 1u)) & 0xffff0000u;
    return bx | by;
}
static __device__ __forceinline__ float bf_lo(unsigned u) { return __uint_as_float(u << 16); }
static __device__ __forceinline__ float bf_hi(unsigned u) { return __uint_as_float(u & 0xffff0000u); }

// ---------------------------------------------------------------------------
// bucket histogram (LDS-aggregated)
__global__ __launch_bounds__(256) void k_hist(const int* __restrict__ dst,
                                              int* __restrict__ bcnt, int E) {
    __shared__ int hist[256];
    hist[threadIdx.x] = 0;
    __syncthreads();
    for (int e = blockIdx.x * 256 + threadIdx.x; e < E; e += gridDim.x * 256)
        atomicAdd(&hist[dst[e] >> BSHIFT], 1);
    __syncthreads();
    const int v = hist[threadIdx.x];
    if (v) atomicAdd(&bcnt[threadIdx.x], v);
}

// bucket exclusive scan; also zero the dummy ybf row N
__global__ __launch_bounds__(256) void k_bscan(const int* __restrict__ bcnt,
                                               int* __restrict__ bbase, int* __restrict__ pcur,
                                               unsigned* __restrict__ ybf, int NB, int E, int N) {
    __shared__ int l[256];
    const int t = threadIdx.x;
    const int v = (t < NB) ? bcnt[t] : 0;
    l[t] = v;
    __syncthreads();
    for (int off = 1; off < 256; off <<= 1) {
        int x = l[t];
        if (t >= off) x += l[t - off];
        __syncthreads();
        l[t] = x;
        __syncthreads();
    }
    const int excl = l[t] - v;
    if (t < NB) { bbase[t] = excl; pcur[t] = excl; }
    if (t == 0) bbase[NB] = E;
    if (t < 32) ybf[(size_t)N * 32 + t] = 0u;     // dummy zero row for padded gathers
}

// LDS radix-partition: one chunk per block, grouped coalesced writes of packed uint
__global__ __launch_bounds__(256) void k_part(const int* __restrict__ src,
                                              const int* __restrict__ dst,
                                              int* __restrict__ pcur,
                                              unsigned* __restrict__ arena, int E) {
    __shared__ unsigned stage[CHUNK];
    __shared__ unsigned char bktb[CHUNK];
    __shared__ int hist[256], lofs[256], gbase[256];
    const int t = threadIdx.x;
    const int e0 = blockIdx.x * CHUNK;
    const int cn = min(CHUNK, E - e0);

    hist[t] = 0;
    __syncthreads();
    for (int i = t; i < cn; i += 256)
        atomicAdd(&hist[dst[e0 + i] >> BSHIFT], 1);
    __syncthreads();
    const int v = hist[t];
    lofs[t] = v;
    __syncthreads();
    for (int off = 1; off < 256; off <<= 1) {
        int x = lofs[t];
        if (t >= off) x += lofs[t - off];
        __syncthreads();
        lofs[t] = x;
        __syncthreads();
    }
    const int excl = lofs[t] - v;
    __syncthreads();
    lofs[t] = excl;
    if (v > 0) gbase[t] = atomicAdd(&pcur[t], v);
    __syncthreads();
    for (int i = t; i < cn; i += 256) {
        const int dd = dst[e0 + i];
        const int b  = dd >> BSHIFT;
        const int p  = atomicAdd(&lofs[b], 1);
        stage[p] = ((unsigned)(dd & (BUCKET - 1)) << 23) | (unsigned)src[e0 + i];
        bktb[p]  = (unsigned char)b;
    }
    __syncthreads();
    for (int i = t; i < cn; i += 256) {
        const int b = bktb[i];
        const int startb = lofs[b] - hist[b];
        arena[gbase[b] + (i - startb)] = stage[i];
    }
}

// per-bucket CSR build with 8-padding; rp/pcnt/dinv/colbuf
__global__ __launch_bounds__(512) void k_build(const unsigned* __restrict__ arena,
                                               const int* __restrict__ bbase,
                                               int* __restrict__ rp, int* __restrict__ pcnt,
                                               int* __restrict__ colbuf, float* __restrict__ dinv,
                                               int N) {
    __shared__ int ncnt[512], sc[512], lcur[512];
    const int t = threadIdx.x;
    const int nbase  = blockIdx.x << BSHIFT;
    const int nlocal = min(BUCKET, N - nbase);
    const int abeg = bbase[blockIdx.x];
    const int aend = bbase[blockIdx.x + 1];
    const int pbase = abeg + 7 * nbase;           // padded-region base (disjoint per bucket)

    ncnt[t] = 0;
    __syncthreads();
    for (int i = abeg + t; i < aend; i += 512)
        atomicAdd(&ncnt[arena[i] >> 23], 1);
    __syncthreads();
    const int v = ncnt[t];
    const int p = (v + 7) & ~7;                   // pad to multiple of 8
    sc[t] = p;
    __syncthreads();
    for (int off = 1; off < 512; off <<= 1) {
        int x = sc[t];
        if (t >= off) x += sc[t - off];
        __syncthreads();
        sc[t] = x;
        __syncthreads();
    }
    const int excl = sc[t] - p;
    lcur[t] = pbase + excl;
    if (t < nlocal) {
        rp[nbase + t]   = pbase + excl;
        pcnt[nbase + t] = p;
        dinv[nbase + t] = rsqrtf((float)v + 1.0f);
    }
    __syncthreads();
    for (int i = abeg + t; i < aend; i += 512) {
        const unsigned u = arena[i];
        const int pos = atomicAdd(&lcur[u >> 23], 1);
        colbuf[pos] = (int)(u & 0x7FFFFFu);
    }
    if (t < nlocal)
        for (int k = v; k < p; ++k) colbuf[pbase + excl + k] = N;   // dummy edges
}

// ---------------------------------------------------------------------------
// gemm with folded BN affine: ybf[row] = pack_bf16(((sc*x+sh) @ W + ) * dinv[row])
__global__ __launch_bounds__(256) void k_gemm(const float* __restrict__ x,
                                              const float* __restrict__ W,
                                              const float* __restrict__ stats,
                                              const float* __restrict__ gamma,
                                              const float* __restrict__ beta,
                                              const float* __restrict__ dinv,
                                              unsigned* __restrict__ ybf,
                                              float invN, int affine, int N) {
    __shared__ float scs[D], shs[D];
    const int tid = threadIdx.x;
    if (tid < D) {
        float sc = 1.f, sh = 0.f;
        if (affine) {
            const float mu  = stats[tid] * invN;
            const float var = stats[D + tid] * invN - mu * mu;
            sc = gamma[tid] * rsqrtf(var + BN_EPS);
            sh = beta[tid] - mu * sc;
        }
        scs[tid] = sc; shs[tid] = sh;
    }
    __syncthreads();

    const int lane = tid & 63;
    const int wib  = tid >> 6;
    float Wreg[D];
    float bv = 0.f;
#pragma unroll
    for (int k = 0; k < D; ++k) {
        const float w = W[k * D + lane];
        Wreg[k] = scs[k] * w;
        bv = fmaf(shs[k], w, bv);
    }
    const int stride = gridDim.x * 4;
    for (int row = __builtin_amdgcn_readfirstlane(blockIdx.x * 4 + wib); row < N; row += stride) {
        const float4* xr = (const float4*)(x + (size_t)row * D);
        float acc = 0.f;
#pragma unroll
        for (int k4 = 0; k4 < 16; ++k4) {
            const float4 xv = xr[k4];
            acc = fmaf(xv.x, Wreg[4 * k4 + 0], acc);
            acc = fmaf(xv.y, Wreg[4 * k4 + 1], acc);
            acc = fmaf(xv.z, Wreg[4 * k4 + 2], acc);
            acc = fmaf(xv.w, Wreg[4 * k4 + 3], acc);
        }
        const float r  = (acc + bv) * dinv[row];
        const float rn = __shfl_down(r, 1, 64);
        if (!(lane & 1))
            ybf[(size_t)row * 32 + (lane >> 1)] = pk_bf16(r, rn);
    }
}

// ---------------------------------------------------------------------------
// pull: half-wave per node (32 lanes = full row), padded edges -> no inner masking.
__global__ __launch_bounds__(256) void k_pull(const int* __restrict__ rp,
                                              const int* __restrict__ pcnt,
                                              const int* __restrict__ colbuf,
                                              const unsigned* __restrict__ ybf,
                                              const float* __restrict__ dinv,
                                              const float* __restrict__ b,
                                              float* __restrict__ h,
                                              float* __restrict__ stats, int N) {
    const int tid  = threadIdx.x;
    const int lane = tid & 63;
    const int t32  = lane & 31;
    const int hw   = lane >> 5;
    const int wv   = tid >> 6;
    const float b0 = b[2 * t32];
    const float b1 = b[2 * t32 + 1];
    float s1a = 0.f, s1b = 0.f, s2a = 0.f, s2b = 0.f;

    const int gw = blockIdx.x * 4 + wv;
    const int gstride = gridDim.x * 4;

    for (int pr = gw; 2 * pr < N; pr += gstride) {
        const int n  = 2 * pr + hw;
        const bool vn = n < N;
        const int st = vn ? rp[n]   : 0;
        const int pd = vn ? pcnt[n] : 0;

        float a[8][2];
#pragma unroll
        for (int c = 0; c < 8; ++c) { a[c][0] = 0.f; a[c][1] = 0.f; }
        {   // self term
            const unsigned u = vn ? ybf[(size_t)n * 32 + t32] : 0u;
            a[0][0] = bf_lo(u); a[0][1] = bf_hi(u);
        }
        for (int w0 = 0; w0 < pd; w0 += 32) {
            const int wn = min(pd - w0, 32);                 // multiple of 8
            const int ci = (t32 < wn) ? colbuf[st + w0 + t32] : 0;
            for (int j0 = 0; j0 < wn; j0 += 8) {
#pragma unroll
                for (int jj = 0; jj < 8; ++jj) {
                    const int idx = __shfl(ci, hw * 32 + j0 + jj, 64);
                    const unsigned u = ybf[(size_t)idx * 32 + t32];
                    a[jj][0] += bf_lo(u);
                    a[jj][1] += bf_hi(u);
                }
            }
        }
        const float v0 = ((a[0][0] + a[1][0]) + (a[2][0] + a[3][0])) +
                         ((a[4][0] + a[5][0]) + (a[6][0] + a[7][0]));
        const float v1 = ((a[0][1] + a[1][1]) + (a[2][1] + a[3][1])) +
                         ((a[4][1] + a[5][1]) + (a[6][1] + a[7][1]));
        if (vn) {
            const float di = dinv[n];
            float t0 = fmaf(di, v0, b0); t0 = t0 > 0.f ? t0 : SLOPE * t0;
            float t1 = fmaf(di, v1, b1); t1 = t1 > 0.f ? t1 : SLOPE * t1;
            *(float2*)&h[(size_t)n * D + 2 * t32] = make_float2(t0, t1);
            s1a += t0; s2a += t0 * t0;
            s1b += t1; s2b += t1 * t1;
        }
    }

    __shared__ float l1[64], l2[64];
    if (tid < 64) { l1[tid] = 0.f; l2[tid] = 0.f; }
    __syncthreads();
    atomicAdd(&l1[2 * t32],     s1a);
    atomicAdd(&l1[2 * t32 + 1], s1b);
    atomicAdd(&l2[2 * t32],     s2a);
    atomicAdd(&l2[2 * t32 + 1], s2b);
    __syncthreads();
    if (tid < 64) {
        atomicAdd(&stats[tid],      l1[tid]);
        atomicAdd(&stats[64 + tid], l2[tid]);
    }
}

// ---------------------------------------------------------------------------
__global__ __launch_bounds__(256) void k_normalize(const float* __restrict__ h,
                                                   const float* __restrict__ stats,
                                                   const float* __restrict__ gamma,
                                                   const float* __restrict__ beta,
                                                   float* __restrict__ out,
                                                   float invN, int total4) {
    const int gt = blockIdx.x * 256 + threadIdx.x;
    const int c0 = (gt * 4) & 63;
    float sc[4], sh[4];
#pragma unroll
    for (int k = 0; k < 4; ++k) {
        const int c = c0 + k;
        const float mu  = stats[c] * invN;
        const float var = stats[64 + c] * invN - mu * mu;
        sc[k] = gamma[c] * rsqrtf(var + BN_EPS);
        sh[k] = beta[c] - mu * sc[k];
    }
    const float4* h4 = (const float4*)h;
    float4* o4 = (float4*)out;
    for (int i = gt; i < total4; i += gridDim.x * 256) {
        float4 v = h4[i];
        v.x = fmaf(sc[0], v.x, sh[0]);
        v.y = fmaf(sc[1], v.y, sh[1]);
        v.z = fmaf(sc[2], v.z, sh[2]);
        v.w = fmaf(sc[3], v.w, sh[3]);
        o4[i] = v;
    }
}

// ---------------------------------------------------------------------------
extern "C" void kernel_launch(void* const* d_in, const int* in_sizes, int n_in,
                              void* d_out, int out_size, void* d_ws, size_t ws_size,
                              hipStream_t stream) {
    const float* x0     = (const float*)d_in[0];
    const int*   ei     = (const int*)d_in[1];
    const float* Ws     = (const float*)d_in[2];
    const float* bs     = (const float*)d_in[3];
    const float* gammas = (const float*)d_in[4];
    const float* betas  = (const float*)d_in[5];

    const int N = in_sizes[0] / D;
    const int E = in_sizes[1] / 2;
    const int L = in_sizes[2] / (D * D);
    const int NB = (N + BUCKET - 1) >> BSHIFT;
    const int nchunks = (E + CHUNK - 1) / CHUNK;

    const int* srcp = ei;
    const int* dstp = ei + E;

    char* wsb = (char*)d_ws;
    size_t o = 0;
    auto alloc = [&](size_t elems) { size_t r = o; o += (elems + 255) & ~(size_t)255; return r; };
    const size_t o_bcnt  = alloc(256);                      // int, zeroed
    const size_t o_stats = alloc((size_t)L * 128);          // float, zeroed
    const size_t zero_end = o;
    const size_t o_bbase = alloc(257);                      // int
    const size_t o_pcur  = alloc(256);                      // int
    const size_t o_rp    = alloc((size_t)N);                // int
    const size_t o_pcnt  = alloc((size_t)N);                // int
    const size_t o_dinv  = alloc((size_t)N);                // float
    const size_t o_arena = alloc((size_t)E);                // uint (packed)
    const size_t o_col   = alloc((size_t)E + 7 * (size_t)N + 64);  // int (padded)
    const size_t o_y     = alloc(((size_t)N + 1) * 32);     // uint (bf16x2), +1 dummy row
    const size_t o_h     = alloc((size_t)N * D);            // float

    int*      bcnt  = (int*)(wsb + o_bcnt * 4);
    float*    stats = (float*)(wsb + o_stats * 4);
    int*      bbase = (int*)(wsb + o_bbase * 4);
    int*      pcur  = (int*)(wsb + o_pcur * 4);
    int*      rp    = (int*)(wsb + o_rp * 4);
    int*      pcnt  = (int*)(wsb + o_pcnt * 4);
    float*    dinv  = (float*)(wsb + o_dinv * 4);
    unsigned* arena = (unsigned*)(wsb + o_arena * 4);
    int*      col   = (int*)(wsb + o_col * 4);
    unsigned* ybf   = (unsigned*)(wsb + o_y * 4);
    float*    h     = (float*)(wsb + o_h * 4);
    float*    out   = (float*)d_out;

    hipMemsetAsync(d_ws, 0, zero_end * 4, stream);

    k_hist <<<512, 256, 0, stream>>>(dstp, bcnt, E);
    k_bscan<<<1,   256, 0, stream>>>(bcnt, bbase, pcur, ybf, NB, E, N);
    k_part <<<nchunks, 256, 0, stream>>>(srcp, dstp, pcur, arena, E);
    k_build<<<NB,  512, 0, stream>>>(arena, bbase, rp, pcnt, col, dinv, N);

    const float invN = 1.0f / (float)N;
    const float* xin = x0;
    for (int l = 0; l < L; ++l) {
        const int pl = l ? l - 1 : 0;
        k_gemm<<<1024, 256, 0, stream>>>(xin, Ws + (size_t)l * D * D,
                                         stats + (size_t)pl * 128,
                                         gammas + (size_t)pl * D, betas + (size_t)pl * D,
                                         dinv, ybf, invN, l > 0 ? 1 : 0, N);
        k_pull<<<2048, 256, 0, stream>>>(rp, pcnt, col, ybf, dinv, bs + (size_t)l * D,
                                         h, stats + (size_t)l * 128, N);
        xin = h;
    }
    k_normalize<<<1024, 256, 0, stream>>>(h, stats + (size_t)(L - 1) * 128,
                                          gammas + (size_t)(L - 1) * D,
                                          betas + (size_t)(L - 1) * D,
                                          out, invN, N * D / 4);
}